// Round 16
// baseline (71.122 us; speedup 1.0000x reference)
//
#include <hip/hip_runtime.h>
#include <hip/hip_bf16.h>

#define NN 4096
#define DD 256
#define CCN 8    // col chunks (512 cols each)
#define TPB 16   // 32-col tiles per block
#define LOG2E 1.44269504088896f

typedef __attribute__((ext_vector_type(8))) short bf16x8;
typedef __attribute__((ext_vector_type(4))) float f32x4;
typedef __attribute__((ext_vector_type(2))) float f32x2;

typedef const unsigned int __attribute__((address_space(1)))* gu32p;
typedef unsigned int __attribute__((address_space(3)))* su32p;

__device__ __forceinline__ float fexp2(float x) { return __builtin_amdgcn_exp2f(x); }

// ---- kernel 1: L2-normalize rows (one row/wave) + per-row label-kernel sums T ----
__global__ __launch_bounds__(256) void k_norm(const float* __restrict__ zi,
                                              const float* __restrict__ zj,
                                              const float* __restrict__ labels,
                                              __hip_bfloat16* __restrict__ oi,
                                              __hip_bfloat16* __restrict__ oj,
                                              float* __restrict__ T,
                                              float* __restrict__ out) {
  __shared__ float Tred[2][2];
  if (blockIdx.x == 0 && threadIdx.x == 0) out[0] = 0.f;  // replaces memset dispatch
  int gw = (blockIdx.x * 256 + threadIdx.x) >> 6;
  int lane = threadIdx.x & 63;
  int wave = threadIdx.x >> 6;
  const float* src = (gw < NN) ? zi : zj;
  __hip_bfloat16* dst = (gw < NN) ? oi : oj;
  int row = (gw < NN) ? gw : gw - NN;
  float4 v = ((const float4*)(src + (size_t)row * DD))[lane];
  float ss = v.x * v.x + v.y * v.y + v.z * v.z + v.w * v.w;
#pragma unroll
  for (int m = 1; m < 64; m <<= 1) ss += __shfl_xor(ss, m);
  float s = 1.0f / fmaxf(sqrtf(ss), 1e-12f);
  __hip_bfloat16* d = dst + (size_t)row * DD + lane * 4;
  d[0] = __float2bfloat16(v.x * s);
  d[1] = __float2bfloat16(v.y * s);
  d[2] = __float2bfloat16(v.z * s);
  d[3] = __float2bfloat16(v.w * s);

  // T[r] = sum_c exp(-0.5*(lab_r - lab_c)^2), r = 2*blockIdx + (wave&1)
  {
    int r = blockIdx.x * 2 + (wave & 1);
    int h = wave >> 1;
    float lr = labels[r];
    float acc = 0.f;
    for (int it = h * 32; it < h * 32 + 32; ++it) {
      float dl = lr - labels[it * 64 + lane];
      acc += fexp2(dl * dl * (-0.5f * LOG2E));
    }
#pragma unroll
    for (int m = 1; m < 64; m <<= 1) acc += __shfl_xor(acc, m);
    if (lane == 0) Tred[wave & 1][h] = acc;
  }
  __syncthreads();
  if (threadIdx.x < 2)
    T[blockIdx.x * 2 + threadIdx.x] = Tred[threadIdx.x][0] + Tred[threadIdx.x][1];
}

// ---- epilogue core: packed-f32 per-element stats (32-col tile: cf = 0..1) ----
// MODE 0 normal; MODE 1 ij diag tile (record diag); MODE 2 ii/jj diag tile (mask rg==cg)
template <int MODE, bool COL>
__device__ __forceinline__ void epi(
    const f32x4 acc[2][2], const f32x2 labr[2][2], const float* __restrict__ labels,
    f32x2 rA[2][2], f32x2 rB[2][2], f32x2 rC[2][2],
    f32x2 cw2[2][3], float* __restrict__ diag,
    int rowbase, int colbase, int wave, int fr, int kg) {
#pragma unroll
  for (int cf = 0; cf < 2; ++cf) {
    const int cg = colbase + cf * 16 + fr;
    const float labc = labels[cg];
    const f32x2 labc2 = {labc, labc};
#pragma unroll
    for (int sub = 0; sub < 2; ++sub) {
#pragma unroll
      for (int pp = 0; pp < 2; ++pp) {
        f32x2 S = {acc[sub][cf][2 * pp], acc[sub][cf][2 * pp + 1]};
        f32x2 arg = S * (2.f * LOG2E) + (-2.f * LOG2E);
        f32x2 b;
        b.x = fexp2(arg.x);
        b.y = fexp2(arg.y);
        f32x2 b2 = b * b;
        f32x2 b5 = b2 * b2 * b;  // exp(S/0.1 - 10) = b^5
        f32x2 dl = labr[sub][pp] - labc2;
        f32x2 e = (dl * (-0.5f * LOG2E)) * dl;
        f32x2 kk;
        kk.x = fexp2(e.x);
        kk.y = fexp2(e.y);
        f32x2 ks = kk * S;
        if (MODE != 0) {
          const int rg = rowbase + wave * 32 + sub * 16 + kg * 4 + 2 * pp;
          if (MODE == 1) {
            if (rg == cg) diag[cg] = S.x;
            if (rg + 1 == cg) diag[cg] = S.y;
          } else {
            if (rg == cg)     { b5.x = 0.f; b.x = 0.f; ks.x = 0.f; }
            if (rg + 1 == cg) { b5.y = 0.f; b.y = 0.f; ks.y = 0.f; }
          }
        }
        rA[sub][pp] += b5;
        rB[sub][pp] += b;
        rC[sub][pp] += ks;
        if (COL) {
          cw2[cf][0] += b5;
          cw2[cf][1] += b;
          cw2[cf][2] += ks;
        }
      }
    }
  }
}

// ---- kernel 2: fused similarity passes, T15 double-pipeline + phase-stagger ----
// Per-block tile-order rotation ph = (by + cc*3 + combo*5) & 15: the 3 blocks
// resident per CU run the same-period loop; without stagger they phase-lock
// (all waves stall on DMA-drain/barrier simultaneously — measured 62% of wall
// with only 38% issue-busy, and immune to TLP/vmcnt/setprio knobs r8-r14).
// Rotation puts co-resident blocks at different loop phases for the whole
// dispatch. Work/addressing unchanged (colp/diag indexed by physical tile).
// combo 0: ij (rows->planes 0/3/6, col partials->colp = ji stats, diag record)
// combo 1: ii (rows->planes 1/4/7, diag masked)
// combo 2: jj (rows->planes 2/5/8, diag masked)
// launch_bounds (256,2): tighter caps spill A-frags (r4/r5/r7 lesson).
__global__ __launch_bounds__(256, 2) void k_main(
    const __hip_bfloat16* __restrict__ zin, const __hip_bfloat16* __restrict__ zjn,
    const float* __restrict__ labels,
    float* __restrict__ part, float* __restrict__ colp, float* __restrict__ diag) {
  __shared__ short lB[2][32 * 256];  // 2 x 16KB double buffer, swizzled content

  const int cc = blockIdx.x;
  const int by = blockIdx.y;
  const int combo = blockIdx.z;
  const bool COLF = (combo == 0);

  const __hip_bfloat16* Ap = (combo == 2) ? zjn : zin;
  const __hip_bfloat16* Bp = (combo == 1) ? zin : zjn;

  const int tid = threadIdx.x;
  const int lane = tid & 63;
  const int wave = tid >> 6;
  const int fr = lane & 15;
  const int kg = lane >> 4;
  const int rowbase = by * 128;
  char* lBc = (char*)lB;

  // A fragments in registers: 2 sub-frags x 8 k-slices (64 VGPR)
  bf16x8 a[2][8];
#pragma unroll
  for (int sub = 0; sub < 2; ++sub) {
    const __hip_bfloat16* Ar =
        Ap + (size_t)(rowbase + wave * 32 + sub * 16 + fr) * DD + kg * 8;
#pragma unroll
    for (int k = 0; k < 8; ++k) a[sub][k] = *(const bf16x8*)(Ar + k * 32);
  }

  f32x2 labr[2][2];
#pragma unroll
  for (int sub = 0; sub < 2; ++sub)
#pragma unroll
    for (int pp = 0; pp < 2; ++pp) {
      const float* lp = labels + rowbase + wave * 32 + sub * 16 + kg * 4 + 2 * pp;
      labr[sub][pp] = (f32x2){lp[0], lp[1]};
    }

  f32x2 rA[2][2] = {}, rB[2][2] = {}, rC[2][2] = {};

  // swizzled B read base: byte = (row*512 + k*64 + kg*16) ^ ((row&7)<<4), row = cf*16+fr
  const int frb = (fr >> 2) & 1;
  const int P0 = fr * 512 + ((kg ^ (fr & 3)) << 4) + (frb << 6);

  // stage 32-row tile t (16KB) into buffer `buf`; source pre-swizzled, LDS linear
#define STAGE(t, buf)                                                         \
  {                                                                           \
    const char* Bt = (const char*)Bp + (size_t)(cc * 512 + (t) * 32) * 512;   \
    char* dst = lBc + (buf) * 16384;                                          \
    _Pragma("unroll") for (int j = 0; j < 4; ++j) {                           \
      int f = tid + 256 * j;                                                  \
      int g = f ^ ((f >> 5) & 7);                                             \
      __builtin_amdgcn_global_load_lds(                                       \
          (gu32p)(const void*)(Bt + (size_t)g * 16),                          \
          (su32p)(void*)(dst + (wave * 64 + 256 * j) * 16), 16, 0, 0);        \
    }                                                                         \
  }

  // MFMA one 128x32 tile from LDS buffer into ACC
  auto do_mfma = [&](f32x4 (&ACC)[2][2], const char* cur) {
#pragma unroll
    for (int s2 = 0; s2 < 2; ++s2)
#pragma unroll
      for (int cf = 0; cf < 2; ++cf) ACC[s2][cf] = (f32x4){0.f, 0.f, 0.f, 0.f};
#pragma unroll
    for (int k = 0; k < 8; ++k) {
      const char* bbase = cur + (P0 ^ (k << 6));
#pragma unroll
      for (int cf = 0; cf < 2; ++cf) {
        bf16x8 bv = *(const bf16x8*)(bbase + cf * 8192);
        ACC[0][cf] = __builtin_amdgcn_mfma_f32_16x16x32_bf16(a[0][k], bv, ACC[0][cf], 0, 0, 0);
        ACC[1][cf] = __builtin_amdgcn_mfma_f32_16x16x32_bf16(a[1][k], bv, ACC[1][cf], 0, 0, 0);
      }
    }
  };

  // full epilogue for physical tile te (dispatch + col-partial stores, no LDS)
  auto do_epi = [&](const f32x4 (&ACC)[2][2], int te) {
    const int colbase = cc * 512 + te * 32;
    const unsigned dtt = (unsigned)(te + 16 * cc - 4 * by);  // diag tiles: dtt < 4
    f32x2 cw2[2][3] = {};
    if (COLF) {
      if (dtt < 4u)
        epi<1, true>(ACC, labr, labels, rA, rB, rC, cw2, diag, rowbase, colbase, wave, fr, kg);
      else
        epi<0, true>(ACC, labr, labels, rA, rB, rC, cw2, diag, rowbase, colbase, wave, fr, kg);
      float* cp = colp + ((size_t)(by * 128 + cc * TPB + te) * 4 + wave) * 96;
#pragma unroll
      for (int cf = 0; cf < 2; ++cf)
#pragma unroll
        for (int p = 0; p < 3; ++p) {
          float v = cw2[cf][p].x + cw2[cf][p].y;
          v += __shfl_xor(v, 16);
          v += __shfl_xor(v, 32);
          if (kg == 0) cp[p * 32 + cf * 16 + fr] = v;
        }
    } else {
      if (dtt < 4u)
        epi<2, false>(ACC, labr, labels, rA, rB, rC, cw2, diag, rowbase, colbase, wave, fr, kg);
      else
        epi<0, false>(ACC, labr, labels, rA, rB, rC, cw2, diag, rowbase, colbase, wave, fr, kg);
    }
  };

  f32x4 accA[2][2], accB[2][2];

  // per-block phase: sequence index s -> physical tile (s + ph) & 15
  const int ph = (by + cc * 3 + combo * 5) & 15;
#define PT(s) (((s) + ph) & 15)

  STAGE(PT(0), 0);
  __syncthreads();  // first tile's DMA drained

#pragma unroll
  for (int ss = 0; ss < TPB / 2; ++ss) {
    const int s0 = 2 * ss, s1 = s0 + 1;
    // even slot -> accA from buf0; epilogue of prev odd slot (accB) overlaps
    STAGE(PT(s0 + 1), 1);           // buf1 free: all waves read it last at barrier
    if (s0 > 0) do_epi(accB, PT(s0 - 1));
    do_mfma(accA, lBc);
    __syncthreads();                // DMA(s0+1) drained; buf0 reads done

    // odd slot -> accB from buf1; epilogue of s0 (accA) overlaps
    if (s1 < TPB - 1) STAGE(PT(s1 + 1), 0);
    do_epi(accA, PT(s0));
    do_mfma(accB, lBc + 16384);
    __syncthreads();                // DMA(s1+1) drained; buf1 reads done
  }
  do_epi(accB, PT(TPB - 1));        // drain last slot's epilogue

  // row-stat flush: reduce over 16 fr lanes, plain stores to this block's cc slab
  float* pc = part + (size_t)cc * 9 * NN;
  const int pr = combo;
#pragma unroll
  for (int sub = 0; sub < 2; ++sub)
#pragma unroll
    for (int pp = 0; pp < 2; ++pp)
#pragma unroll
      for (int comp = 0; comp < 2; ++comp) {
        float va = rA[sub][pp][comp], vb = rB[sub][pp][comp], vc = rC[sub][pp][comp];
#pragma unroll
        for (int m = 1; m < 16; m <<= 1) {
          va += __shfl_xor(va, m);
          vb += __shfl_xor(vb, m);
          vc += __shfl_xor(vc, m);
        }
        if (fr == 0) {
          int r = rowbase + wave * 32 + sub * 16 + kg * 4 + 2 * pp + comp;
          pc[pr * NN + r] = va;
          pc[(3 + pr) * NN + r] = vb;
          pc[(6 + pr) * NN + r] = vc;
        }
      }
}

// ---- kernel 3: gather partials, finalize scalar loss (4 threads per row) ----
__global__ __launch_bounds__(256) void k_final(
    const float* __restrict__ part, const float* __restrict__ colp,
    const float* __restrict__ diag, const float* __restrict__ T,
    float* __restrict__ out) {
  int r = blockIdx.x * 64 + (threadIdx.x >> 2);
  int q = threadIdx.x & 3;
  float st[9];
#pragma unroll
  for (int p = 0; p < 9; ++p) {
    float s = 0.f;
#pragma unroll
    for (int c = 0; c < CCN; ++c) s += part[((size_t)c * 9 + p) * NN + r];
    st[p] = s;
  }
  // ji-side stats = ij column partials for column r (by-range split across q)
  float a3 = 0.f, b3 = 0.f, c3 = 0.f;
  const int cct = r >> 5, c31 = r & 31;  // global col-tile = r/32
  for (int by = 8 * q; by < 8 * q + 8; ++by) {
    const float* cp = colp + (size_t)(by * 128 + cct) * 4 * 96;
#pragma unroll
    for (int w = 0; w < 4; ++w) {
      a3 += cp[w * 96 + c31];
      b3 += cp[w * 96 + 32 + c31];
      c3 += cp[w * 96 + 64 + c31];
    }
  }
  a3 += __shfl_xor(a3, 1); a3 += __shfl_xor(a3, 2);
  b3 += __shfl_xor(b3, 1); b3 += __shfl_xor(b3, 2);
  c3 += __shfl_xor(c3, 1); c3 += __shfl_xor(c3, 2);

  float v = 0.f;
  if (q == 0) {
    float d = diag[r];
    // planes: 0..2 A(ij,ii,jj), 3..5 B, 6..8 C
    float accP = logf(st[0] + st[1]) + logf(a3 + st[2]) + 20.f - 20.f * d;
    float nrm = 2.f * T[r] - 1.f;
    float W = 2.f * (st[6] + st[7] + c3 + st[8]) / nrm;
    float accS = logf(st[3] + st[4]) + logf(b3 + st[5]) + 4.f - W - 2.f * logf(nrm);
    v = accP + accS;
  }
#pragma unroll
  for (int m = 1; m < 64; m <<= 1) v += __shfl_xor(v, m);
  __shared__ float red[4];
  if ((threadIdx.x & 63) == 0) red[threadIdx.x >> 6] = v;
  __syncthreads();
  if (threadIdx.x == 0)
    atomicAdd(out, 0.5f * (red[0] + red[1] + red[2] + red[3]) / (float)NN);
}

extern "C" void kernel_launch(void* const* d_in, const int* in_sizes, int n_in,
                              void* d_out, int out_size, void* d_ws, size_t ws_size,
                              hipStream_t stream) {
  const float* zi = (const float*)d_in[0];
  const float* zj = (const float*)d_in[1];
  const float* labels = (const float*)d_in[2];
  float* out = (float*)d_out;

  char* ws = (char*)d_ws;
  __hip_bfloat16* zinH = (__hip_bfloat16*)ws;                          // 2 MB
  __hip_bfloat16* zjnH = (__hip_bfloat16*)(ws + (size_t)NN * DD * 2);  // 2 MB
  float* part = (float*)(ws + (size_t)NN * DD * 4);                    // 8*9*NN floats
  float* colp = part + (size_t)CCN * 9 * NN;                           // 4096*4*96 floats
  float* diag = colp + (size_t)4096 * 4 * 96;                          // NN floats
  float* T = diag + NN;                                                // NN floats

  k_norm<<<2 * NN / 4, 256, 0, stream>>>(zi, zj, labels, zinH, zjnH, T, out);

  dim3 grid(CCN, NN / 128, 3);
  k_main<<<grid, 256, 0, stream>>>(zinH, zjnH, labels, part, colp, diag);

  k_final<<<NN / 64, 256, 0, stream>>>(part, colp, diag, T, out);
}

// Round 18
// 70.328 us; speedup vs baseline: 1.0113x; 1.0113x over previous
//
#include <hip/hip_runtime.h>
#include <hip/hip_bf16.h>

#define NN 4096
#define DD 256
#define CCN 8    // col chunks (512 cols each)
#define TPB 16   // 32-col tiles per block
#define LOG2E 1.44269504088896f

typedef __attribute__((ext_vector_type(8))) short bf16x8;
typedef __attribute__((ext_vector_type(4))) float f32x4;
typedef __attribute__((ext_vector_type(2))) float f32x2;

typedef const unsigned int __attribute__((address_space(1)))* gu32p;
typedef unsigned int __attribute__((address_space(3)))* su32p;

__device__ __forceinline__ float fexp2(float x) { return __builtin_amdgcn_exp2f(x); }

// ---- kernel 1: L2-normalize rows (one row/wave) + per-row label-kernel sums T ----
// T-chain split across 2 waves per row (32 serial exp2 iters each, halves
// combined via LDS).
__global__ __launch_bounds__(256) void k_norm(const float* __restrict__ zi,
                                              const float* __restrict__ zj,
                                              const float* __restrict__ labels,
                                              __hip_bfloat16* __restrict__ oi,
                                              __hip_bfloat16* __restrict__ oj,
                                              float* __restrict__ T,
                                              float* __restrict__ out) {
  __shared__ float Tred[2][2];
  if (blockIdx.x == 0 && threadIdx.x == 0) out[0] = 0.f;  // replaces memset dispatch
  int gw = (blockIdx.x * 256 + threadIdx.x) >> 6;
  int lane = threadIdx.x & 63;
  int wave = threadIdx.x >> 6;
  const float* src = (gw < NN) ? zi : zj;
  __hip_bfloat16* dst = (gw < NN) ? oi : oj;
  int row = (gw < NN) ? gw : gw - NN;
  float4 v = ((const float4*)(src + (size_t)row * DD))[lane];
  float ss = v.x * v.x + v.y * v.y + v.z * v.z + v.w * v.w;
#pragma unroll
  for (int m = 1; m < 64; m <<= 1) ss += __shfl_xor(ss, m);
  float s = 1.0f / fmaxf(sqrtf(ss), 1e-12f);
  __hip_bfloat16* d = dst + (size_t)row * DD + lane * 4;
  d[0] = __float2bfloat16(v.x * s);
  d[1] = __float2bfloat16(v.y * s);
  d[2] = __float2bfloat16(v.z * s);
  d[3] = __float2bfloat16(v.w * s);

  // T[r] = sum_c exp(-0.5*(lab_r - lab_c)^2), r = 2*blockIdx + (wave&1)
  {
    int r = blockIdx.x * 2 + (wave & 1);
    int h = wave >> 1;
    float lr = labels[r];
    float acc = 0.f;
    for (int it = h * 32; it < h * 32 + 32; ++it) {
      float dl = lr - labels[it * 64 + lane];
      acc += fexp2(dl * dl * (-0.5f * LOG2E));
    }
#pragma unroll
    for (int m = 1; m < 64; m <<= 1) acc += __shfl_xor(acc, m);
    if (lane == 0) Tred[wave & 1][h] = acc;
  }
  __syncthreads();
  if (threadIdx.x < 2)
    T[blockIdx.x * 2 + threadIdx.x] = Tred[threadIdx.x][0] + Tred[threadIdx.x][1];
}

// ---- epilogue core: packed-f32 per-element stats (32-col tile: cf = 0..1) ----
// MODE 0 normal; MODE 1 ij diag tile (record diag); MODE 2 ii/jj diag tile (mask rg==cg)
template <int MODE, bool COL>
__device__ __forceinline__ void epi(
    const f32x4 acc[2][2], const f32x2 labr[2][2], const float* __restrict__ labels,
    f32x2 rA[2][2], f32x2 rB[2][2], f32x2 rC[2][2],
    f32x2 cw2[2][3], float* __restrict__ diag,
    int rowbase, int colbase, int wave, int fr, int kg) {
#pragma unroll
  for (int cf = 0; cf < 2; ++cf) {
    const int cg = colbase + cf * 16 + fr;
    const float labc = labels[cg];
    const f32x2 labc2 = {labc, labc};
#pragma unroll
    for (int sub = 0; sub < 2; ++sub) {
#pragma unroll
      for (int pp = 0; pp < 2; ++pp) {
        f32x2 S = {acc[sub][cf][2 * pp], acc[sub][cf][2 * pp + 1]};
        f32x2 arg = S * (2.f * LOG2E) + (-2.f * LOG2E);
        f32x2 b;
        b.x = fexp2(arg.x);
        b.y = fexp2(arg.y);
        f32x2 b2 = b * b;
        f32x2 b5 = b2 * b2 * b;  // exp(S/0.1 - 10) = b^5
        f32x2 dl = labr[sub][pp] - labc2;
        f32x2 e = (dl * (-0.5f * LOG2E)) * dl;
        f32x2 kk;
        kk.x = fexp2(e.x);
        kk.y = fexp2(e.y);
        f32x2 ks = kk * S;
        if (MODE != 0) {
          const int rg = rowbase + wave * 32 + sub * 16 + kg * 4 + 2 * pp;
          if (MODE == 1) {
            if (rg == cg) diag[cg] = S.x;
            if (rg + 1 == cg) diag[cg] = S.y;
          } else {
            if (rg == cg)     { b5.x = 0.f; b.x = 0.f; ks.x = 0.f; }
            if (rg + 1 == cg) { b5.y = 0.f; b.y = 0.f; ks.y = 0.f; }
          }
        }
        rA[sub][pp] += b5;
        rB[sub][pp] += b;
        rC[sub][pp] += ks;
        if (COL) {
          cw2[cf][0] += b5;
          cw2[cf][1] += b;
          cw2[cf][2] += ks;
        }
      }
    }
  }
}

// ---- kernel 2: fused similarity passes, T15 double-pipeline (r10 structure) ----
// Best measured k_main structure (58.1 us). Measured neutral-or-negative here:
// setprio (r14, -3us), counted-vmcnt triple-buffer (r13), wider grid (r11),
// phase-stagger (r16), finer/coarser tiles (r11/r6), cooperative fusion (r17,
// launch fails under harness). Latency-bound plateau: 62% all-wave-stall
// immune to seven orthogonal scheduling interventions.
// combo 0: ij (rows->planes 0/3/6, col partials->colp = ji stats, diag record)
// combo 1: ii (rows->planes 1/4/7, diag masked)
// combo 2: jj (rows->planes 2/5/8, diag masked)
// launch_bounds (256,2): tighter caps spill A-frags (r4/r5/r7 lesson).
__global__ __launch_bounds__(256, 2) void k_main(
    const __hip_bfloat16* __restrict__ zin, const __hip_bfloat16* __restrict__ zjn,
    const float* __restrict__ labels,
    float* __restrict__ part, float* __restrict__ colp, float* __restrict__ diag) {
  __shared__ short lB[2][32 * 256];  // 2 x 16KB double buffer, swizzled content

  const int cc = blockIdx.x;
  const int by = blockIdx.y;
  const int combo = blockIdx.z;
  const bool COLF = (combo == 0);

  const __hip_bfloat16* Ap = (combo == 2) ? zjn : zin;
  const __hip_bfloat16* Bp = (combo == 1) ? zin : zjn;

  const int tid = threadIdx.x;
  const int lane = tid & 63;
  const int wave = tid >> 6;
  const int fr = lane & 15;
  const int kg = lane >> 4;
  const int rowbase = by * 128;
  char* lBc = (char*)lB;

  // A fragments in registers: 2 sub-frags x 8 k-slices (64 VGPR)
  bf16x8 a[2][8];
#pragma unroll
  for (int sub = 0; sub < 2; ++sub) {
    const __hip_bfloat16* Ar =
        Ap + (size_t)(rowbase + wave * 32 + sub * 16 + fr) * DD + kg * 8;
#pragma unroll
    for (int k = 0; k < 8; ++k) a[sub][k] = *(const bf16x8*)(Ar + k * 32);
  }

  f32x2 labr[2][2];
#pragma unroll
  for (int sub = 0; sub < 2; ++sub)
#pragma unroll
    for (int pp = 0; pp < 2; ++pp) {
      const float* lp = labels + rowbase + wave * 32 + sub * 16 + kg * 4 + 2 * pp;
      labr[sub][pp] = (f32x2){lp[0], lp[1]};
    }

  f32x2 rA[2][2] = {}, rB[2][2] = {}, rC[2][2] = {};

  // swizzled B read base: byte = (row*512 + k*64 + kg*16) ^ ((row&7)<<4), row = cf*16+fr
  const int frb = (fr >> 2) & 1;
  const int P0 = fr * 512 + ((kg ^ (fr & 3)) << 4) + (frb << 6);

  // stage 32-row tile t (16KB) into buffer `buf`; source pre-swizzled, LDS linear
#define STAGE(t, buf)                                                         \
  {                                                                           \
    const char* Bt = (const char*)Bp + (size_t)(cc * 512 + (t) * 32) * 512;   \
    char* dst = lBc + (buf) * 16384;                                          \
    _Pragma("unroll") for (int j = 0; j < 4; ++j) {                           \
      int f = tid + 256 * j;                                                  \
      int g = f ^ ((f >> 5) & 7);                                             \
      __builtin_amdgcn_global_load_lds(                                       \
          (gu32p)(const void*)(Bt + (size_t)g * 16),                          \
          (su32p)(void*)(dst + (wave * 64 + 256 * j) * 16), 16, 0, 0);        \
    }                                                                         \
  }

  // MFMA one 128x32 tile from LDS buffer into ACC
  auto do_mfma = [&](f32x4 (&ACC)[2][2], const char* cur) {
#pragma unroll
    for (int s2 = 0; s2 < 2; ++s2)
#pragma unroll
      for (int cf = 0; cf < 2; ++cf) ACC[s2][cf] = (f32x4){0.f, 0.f, 0.f, 0.f};
#pragma unroll
    for (int k = 0; k < 8; ++k) {
      const char* bbase = cur + (P0 ^ (k << 6));
#pragma unroll
      for (int cf = 0; cf < 2; ++cf) {
        bf16x8 bv = *(const bf16x8*)(bbase + cf * 8192);
        ACC[0][cf] = __builtin_amdgcn_mfma_f32_16x16x32_bf16(a[0][k], bv, ACC[0][cf], 0, 0, 0);
        ACC[1][cf] = __builtin_amdgcn_mfma_f32_16x16x32_bf16(a[1][k], bv, ACC[1][cf], 0, 0, 0);
      }
    }
  };

  // full epilogue for tile te (dispatch + col-partial stores, no LDS)
  auto do_epi = [&](const f32x4 (&ACC)[2][2], int te) {
    const int colbase = cc * 512 + te * 32;
    const unsigned dtt = (unsigned)(te + 16 * cc - 4 * by);  // diag tiles: dtt < 4
    f32x2 cw2[2][3] = {};
    if (COLF) {
      if (dtt < 4u)
        epi<1, true>(ACC, labr, labels, rA, rB, rC, cw2, diag, rowbase, colbase, wave, fr, kg);
      else
        epi<0, true>(ACC, labr, labels, rA, rB, rC, cw2, diag, rowbase, colbase, wave, fr, kg);
      float* cp = colp + ((size_t)(by * 128 + cc * TPB + te) * 4 + wave) * 96;
#pragma unroll
      for (int cf = 0; cf < 2; ++cf)
#pragma unroll
        for (int p = 0; p < 3; ++p) {
          float v = cw2[cf][p].x + cw2[cf][p].y;
          v += __shfl_xor(v, 16);
          v += __shfl_xor(v, 32);
          if (kg == 0) cp[p * 32 + cf * 16 + fr] = v;
        }
    } else {
      if (dtt < 4u)
        epi<2, false>(ACC, labr, labels, rA, rB, rC, cw2, diag, rowbase, colbase, wave, fr, kg);
      else
        epi<0, false>(ACC, labr, labels, rA, rB, rC, cw2, diag, rowbase, colbase, wave, fr, kg);
    }
  };

  f32x4 accA[2][2], accB[2][2];

  STAGE(0, 0);
  __syncthreads();  // tile-0 DMA drained

#pragma unroll
  for (int tt = 0; tt < TPB / 2; ++tt) {
    const int t0 = 2 * tt, t1 = 2 * tt + 1;
    // even tile -> accA from buf0; epilogue of t0-1 (accB) overlaps
    STAGE(t0 + 1, 1);               // buf1 free: all waves read it last at barrier
    if (t0 > 0) do_epi(accB, t0 - 1);
    do_mfma(accA, lBc);
    __syncthreads();                // DMA(t0+1) drained; buf0 reads done

    // odd tile -> accB from buf1; epilogue of t0 (accA) overlaps
    if (t1 < TPB - 1) STAGE(t1 + 1, 0);
    do_epi(accA, t0);
    do_mfma(accB, lBc + 16384);
    __syncthreads();                // DMA(t1+1) drained; buf1 reads done
  }
  do_epi(accB, TPB - 1);            // drain last tile's epilogue

  // row-stat flush: reduce over 16 fr lanes, plain stores to this block's cc slab
  float* pc = part + (size_t)cc * 9 * NN;
  const int pr = combo;
#pragma unroll
  for (int sub = 0; sub < 2; ++sub)
#pragma unroll
    for (int pp = 0; pp < 2; ++pp)
#pragma unroll
      for (int comp = 0; comp < 2; ++comp) {
        float va = rA[sub][pp][comp], vb = rB[sub][pp][comp], vc = rC[sub][pp][comp];
#pragma unroll
        for (int m = 1; m < 16; m <<= 1) {
          va += __shfl_xor(va, m);
          vb += __shfl_xor(vb, m);
          vc += __shfl_xor(vc, m);
        }
        if (fr == 0) {
          int r = rowbase + wave * 32 + sub * 16 + kg * 4 + 2 * pp + comp;
          pc[pr * NN + r] = va;
          pc[(3 + pr) * NN + r] = vb;
          pc[(6 + pr) * NN + r] = vc;
        }
      }
}

// ---- kernel 3: gather partials, finalize scalar loss (4 threads per row) ----
__global__ __launch_bounds__(256) void k_final(
    const float* __restrict__ part, const float* __restrict__ colp,
    const float* __restrict__ diag, const float* __restrict__ T,
    float* __restrict__ out) {
  int r = blockIdx.x * 64 + (threadIdx.x >> 2);
  int q = threadIdx.x & 3;
  float st[9];
#pragma unroll
  for (int p = 0; p < 9; ++p) {
    float s = 0.f;
#pragma unroll
    for (int c = 0; c < CCN; ++c) s += part[((size_t)c * 9 + p) * NN + r];
    st[p] = s;
  }
  // ji-side stats = ij column partials for column r (by-range split across q)
  float a3 = 0.f, b3 = 0.f, c3 = 0.f;
  const int cct = r >> 5, c31 = r & 31;  // global col-tile = r/32
  for (int by = 8 * q; by < 8 * q + 8; ++by) {
    const float* cp = colp + (size_t)(by * 128 + cct) * 4 * 96;
#pragma unroll
    for (int w = 0; w < 4; ++w) {
      a3 += cp[w * 96 + c31];
      b3 += cp[w * 96 + 32 + c31];
      c3 += cp[w * 96 + 64 + c31];
    }
  }
  a3 += __shfl_xor(a3, 1); a3 += __shfl_xor(a3, 2);
  b3 += __shfl_xor(b3, 1); b3 += __shfl_xor(b3, 2);
  c3 += __shfl_xor(c3, 1); c3 += __shfl_xor(c3, 2);

  float v = 0.f;
  if (q == 0) {
    float d = diag[r];
    // planes: 0..2 A(ij,ii,jj), 3..5 B, 6..8 C
    float accP = logf(st[0] + st[1]) + logf(a3 + st[2]) + 20.f - 20.f * d;
    float nrm = 2.f * T[r] - 1.f;
    float W = 2.f * (st[6] + st[7] + c3 + st[8]) / nrm;
    float accS = logf(st[3] + st[4]) + logf(b3 + st[5]) + 4.f - W - 2.f * logf(nrm);
    v = accP + accS;
  }
#pragma unroll
  for (int m = 1; m < 64; m <<= 1) v += __shfl_xor(v, m);
  __shared__ float red[4];
  if ((threadIdx.x & 63) == 0) red[threadIdx.x >> 6] = v;
  __syncthreads();
  if (threadIdx.x == 0)
    atomicAdd(out, 0.5f * (red[0] + red[1] + red[2] + red[3]) / (float)NN);
}

extern "C" void kernel_launch(void* const* d_in, const int* in_sizes, int n_in,
                              void* d_out, int out_size, void* d_ws, size_t ws_size,
                              hipStream_t stream) {
  const float* zi = (const float*)d_in[0];
  const float* zj = (const float*)d_in[1];
  const float* labels = (const float*)d_in[2];
  float* out = (float*)d_out;

  char* ws = (char*)d_ws;
  __hip_bfloat16* zinH = (__hip_bfloat16*)ws;                          // 2 MB
  __hip_bfloat16* zjnH = (__hip_bfloat16*)(ws + (size_t)NN * DD * 2);  // 2 MB
  float* part = (float*)(ws + (size_t)NN * DD * 4);                    // 8*9*NN floats
  float* colp = part + (size_t)CCN * 9 * NN;                           // 4096*4*96 floats
  float* diag = colp + (size_t)4096 * 4 * 96;                          // NN floats
  float* T = diag + NN;                                                // NN floats

  k_norm<<<2 * NN / 4, 256, 0, stream>>>(zi, zj, labels, zinH, zjnH, T, out);

  dim3 grid(CCN, NN / 128, 3);
  k_main<<<grid, 256, 0, stream>>>(zinH, zjnH, labels, part, colp, diag);

  k_final<<<NN / 64, 256, 0, stream>>>(part, colp, diag, T, out);
}